// Round 7
// baseline (117.661 us; speedup 1.0000x reference)
//
#include <hip/hip_runtime.h>
#include <hip/hip_bf16.h>

#define BB 8192
#define DD 256
#define ZN (2 * BB)   // floats to zero: S_all, S_1

typedef float f32x4 __attribute__((ext_vector_type(4)));
typedef __bf16 bf16x8 __attribute__((ext_vector_type(8)));

// sqrt(log2(e)/0.07): fn rows pre-scaled so MFMA acc = sim * log2(e)/T directly
#define FSCALE 4.53981600f

// raw v_exp_f32: args here are |x| <= ~21, no range fixup needed
__device__ __forceinline__ float fast_exp2(float x) {
    float r;
    asm("v_exp_f32 %0, %1" : "=v"(r) : "v"(x));
    return r;
}

// ---------------------------------------------------------------------------
// prep: one wave per row. dist_sq vs center, sigma partials (block-reduced,
// race-free into stats_part[block]), writes the normalized+scaled row in MFMA
// FRAGMENT ORDER. Also zeroes S_all/S_1/out.
// ---------------------------------------------------------------------------
__global__ __launch_bounds__(256) void prep_kernel(
    const float* __restrict__ feat, const int* __restrict__ labels,
    const float* __restrict__ center, __hip_bfloat16* __restrict__ fnf,
    float* __restrict__ dist_sq, float* __restrict__ stats_part,
    float* __restrict__ zacc, float* __restrict__ out)
{
    __shared__ float sh[3][4];
    const int gid = blockIdx.x * 256 + threadIdx.x;
    if (gid < ZN) zacc[gid] = 0.0f;
    if (gid == 0) out[0] = 0.0f;

    const int wave = threadIdx.x >> 6;
    const int lane = threadIdx.x & 63;
    const int row  = blockIdx.x * 4 + wave;

    const float4* frow = reinterpret_cast<const float4*>(feat + (size_t)row * DD);
    const float4* crow = reinterpret_cast<const float4*>(center);
    float4 x = frow[lane];
    float4 c = crow[lane];

    float d0 = x.x - c.x, d1 = x.y - c.y, d2 = x.z - c.z, d3 = x.w - c.w;
    float dsq = d0*d0 + d1*d1 + d2*d2 + d3*d3;
    float nsq = x.x*x.x + x.y*x.y + x.z*x.z + x.w*x.w;
    float sx  = x.x + x.y + x.z + x.w;

    #pragma unroll
    for (int m = 1; m < 64; m <<= 1) {
        dsq += __shfl_xor(dsq, m);
        nsq += __shfl_xor(nsq, m);
        sx  += __shfl_xor(sx,  m);
    }

    float rn = FSCALE / fmaxf(sqrtf(nsq), 1e-12f);

    ushort4 u;
    u.x = __builtin_bit_cast(unsigned short, __float2bfloat16(x.x * rn));
    u.y = __builtin_bit_cast(unsigned short, __float2bfloat16(x.y * rn));
    u.z = __builtin_bit_cast(unsigned short, __float2bfloat16(x.z * rn));
    u.w = __builtin_bit_cast(unsigned short, __float2bfloat16(x.w * rn));

    // lane holds elems e=4*lane..+3: kc=lane/8, quad=(lane%8)/2, half=lane&1
    const int g    = row >> 4;
    const int l15r = row & 15;
    const int kc   = lane >> 3;
    const int qd   = (lane & 7) >> 1;
    const int half = lane & 1;
    const size_t cell = (size_t)((g * 8 + kc) * 64 + qd * 16 + l15r);
    reinterpret_cast<ushort4*>(fnf)[cell * 2 + half] = u;

    if (lane == 0) {
        const float m0 = (labels[row] == 0) ? 1.0f : 0.0f;
        dist_sq[row] = dsq;
        sh[0][wave] = m0;
        sh[1][wave] = sx  * m0;
        sh[2][wave] = nsq * m0;
    }
    __syncthreads();
    if (threadIdx.x == 0) {
        float* sp = stats_part + (size_t)blockIdx.x * 4;
        sp[0] = sh[0][0] + sh[0][1] + sh[0][2] + sh[0][3];
        sp[1] = sh[1][0] + sh[1][1] + sh[1][2] + sh[1][3];
        sp[2] = sh[2][0] + sh[2][1] + sh[2][2] + sh[2][3];
        sp[3] = 0.0f;
    }
}

// ---------------------------------------------------------------------------
// gram v8: v7's barrier-free direct-global structure, with de-phased TLP
// doubled (the one new variable).
// v7 evidence: 45us at 2 waves/SIMD (grid-limited), ~3370 cyc/tile/wave vs
// ~700 cyc pipe work, no pipe >30% -> latency-bound with too few wave
// streams. v8: 32 rows/wave (a[2][8]), grid 1024 (64 rb x 16 cs), 4
// blocks/CU via launch_bounds(256,4) -> 16 free-running waves/CU.
// B re-reads within a block are L1-absorbed -> no L2 BW risk.
// ---------------------------------------------------------------------------
#define LOAD4(BV, T, KB)                                                       \
  {                                                                            \
    _Pragma("unroll")                                                          \
    for (int k = 0; k < 4; ++k)                                                \
      BV[k] = F[((size_t)(cpanel + (T)) * 8 + (KB) + k) * 64 + lane];          \
  }

#define MFMA8(BV, KB)                                                          \
  {                                                                            \
    _Pragma("unroll")                                                          \
    for (int k = 0; k < 4; ++k) {                                              \
      acc[0] = __builtin_amdgcn_mfma_f32_16x16x32_bf16(a[0][(KB) + k], BV[k], acc[0], 0, 0, 0); \
      acc[1] = __builtin_amdgcn_mfma_f32_16x16x32_bf16(a[1][(KB) + k], BV[k], acc[1], 0, 0, 0); \
    }                                                                          \
  }

#define EPILOGUE(T)                                                            \
  {                                                                            \
    const int colbase = colstart + (T) * 16;                                   \
    const int bcol = colbase + l15;                                            \
    const float w1 = wlab[(T) * 16 + l15];                                     \
    if (colbase + 16 > rowbase && colbase < rowbase + 32) {                    \
      _Pragma("unroll")                                                        \
      for (int s = 0; s < 2; ++s)                                              \
        _Pragma("unroll")                                                      \
        for (int r = 0; r < 4; ++r) {                                          \
          const int rr = rowbase + s * 16 + quad * 4 + r;                      \
          float e = (rr == bcol) ? 0.0f : fast_exp2(acc[s][r]);                \
          sall[s][r] += e; sp1[s][r] = fmaf(e, w1, sp1[s][r]);                 \
        }                                                                      \
    } else {                                                                   \
      _Pragma("unroll")                                                        \
      for (int s = 0; s < 2; ++s)                                              \
        _Pragma("unroll")                                                      \
        for (int r = 0; r < 4; ++r) {                                          \
          float e = fast_exp2(acc[s][r]);                                      \
          sall[s][r] += e; sp1[s][r] = fmaf(e, w1, sp1[s][r]);                 \
        }                                                                      \
    }                                                                          \
  }

__global__ __launch_bounds__(256, 4) void gram_kernel(
    const __hip_bfloat16* __restrict__ fnf, const int* __restrict__ labels,
    float* __restrict__ S_all, float* __restrict__ S_1)
{
    __shared__ float wlab[512];

    const int tid  = threadIdx.x;
    const int lane = tid & 63;
    const int wave = tid >> 6;
    const int l15  = lane & 15;
    const int quad = lane >> 4;

    // XCD-aware swizzle: 1024 blocks; xcd = bid%8 hosts col-splits {2x,2x+1}
    const int bid = blockIdx.x;
    const int xcd = bid & 7;
    const int j   = bid >> 3;            // 0..127
    const int cs  = xcd * 2 + (j & 1);   // col split 0..15
    const int rb  = j >> 1;              // row block 0..63

    const int rowbase  = rb * 128 + wave * 32;
    const int colstart = cs * 512;
    const int cpanel   = colstart >> 4;  // first 16-col cell group

    const bf16x8* __restrict__ F = reinterpret_cast<const bf16x8*>(fnf);

    // A fragments: 2 sub-tiles x 8 k-chunks = 32 rows/wave, coalesced loads
    bf16x8 a[2][8];
    #pragma unroll
    for (int s = 0; s < 2; ++s)
        #pragma unroll
        for (int kc = 0; kc < 8; ++kc)
            a[s][kc] = F[(size_t)((((rowbase >> 4) + s) * 8 + kc)) * 64 + lane];

    float sall[2][4], sp1[2][4];
    #pragma unroll
    for (int s = 0; s < 2; ++s)
        #pragma unroll
        for (int r = 0; r < 4; ++r) { sall[s][r] = 0.0f; sp1[s][r] = 0.0f; }

    #pragma unroll
    for (int i = tid; i < 512; i += 256) wlab[i] = (float)labels[colstart + i];
    __syncthreads();        // the ONLY barrier; waves de-phase after this

    f32x4 acc[2];
    bf16x8 bvP[4], bvC[4];  // fixed roles: bvP = lo(next), bvC = hi(current)

    LOAD4(bvP, 0, 0);       // prefetch tile 0 lo-half

    #pragma unroll 1
    for (int t = 0; t < 31; ++t) {
        LOAD4(bvC, t, 4);           // current hi-half, in flight under MFMA-lo
        acc[0] = (f32x4){0,0,0,0}; acc[1] = (f32x4){0,0,0,0};
        MFMA8(bvP, 0);              // consume lo (prefetched last tile)
        LOAD4(bvP, t + 1, 0);       // prefetch next lo (WAR: after consume)
        MFMA8(bvC, 4);              // vmcnt wait for bvC folds under MFMA-lo
        EPILOGUE(t);
    }
    // t == 31
    LOAD4(bvC, 31, 4);
    acc[0] = (f32x4){0,0,0,0}; acc[1] = (f32x4){0,0,0,0};
    MFMA8(bvP, 0);
    MFMA8(bvC, 4);
    EPILOGUE(31);

    // reduce over the 16 cols held across low lane bits, one atomic/row/block
    #pragma unroll
    for (int s = 0; s < 2; ++s)
        #pragma unroll
        for (int r = 0; r < 4; ++r) {
            float va = sall[s][r];
            float v1 = sp1[s][r];
            #pragma unroll
            for (int m = 1; m < 16; m <<= 1) {
                va += __shfl_xor(va, m);
                v1 += __shfl_xor(v1, m);
            }
            if (l15 == 0) {
                const int grow = rowbase + s * 16 + quad * 4 + r;
                atomicAdd(&S_all[grow], va);
                atomicAdd(&S_1[grow],  v1);
            }
        }
}

// ---------------------------------------------------------------------------
// finalize: fold 2048 sigma partials (redundantly per block, coalesced
// float4), then per-row losses + mean reduction into out[0].
// ---------------------------------------------------------------------------
__global__ __launch_bounds__(256) void finalize_kernel(
    const int* __restrict__ labels, const float* __restrict__ dist_sq,
    const float* __restrict__ S_all, const float* __restrict__ S_1,
    const float* __restrict__ stats_part, const float* __restrict__ rsigma,
    float* __restrict__ out)
{
    __shared__ float sh[3][4];
    const int lane = threadIdx.x & 63;
    const int wave = threadIdx.x >> 6;

    float c = 0.0f, s = 0.0f, q = 0.0f;
    const float4* sp = reinterpret_cast<const float4*>(stats_part);
    #pragma unroll
    for (int b = 0; b < 8; ++b) {
        const float4 v = sp[b * 256 + threadIdx.x];
        c += v.x; s += v.y; q += v.z;
    }
    #pragma unroll
    for (int m = 1; m < 64; m <<= 1) {
        c += __shfl_xor(c, m);
        s += __shfl_xor(s, m);
        q += __shfl_xor(q, m);
    }
    if (lane == 0) { sh[0][wave] = c; sh[1][wave] = s; sh[2][wave] = q; }
    __syncthreads();

    const float n0   = sh[0][0] + sh[0][1] + sh[0][2] + sh[0][3];
    const float ssx  = sh[1][0] + sh[1][1] + sh[1][2] + sh[1][3];
    const float snsq = sh[2][0] + sh[2][1] + sh[2][2] + sh[2][3];

    const float n_el = n0 * (float)DD;
    const float mean = ssx / n_el;
    const float var  = (snsq - n_el * mean * mean) / (n_el - 1.0f);
    const float sigma_new  = 0.9f * rsigma[0] + 0.1f * sqrtf(var);
    const float m_adaptive = 0.5f + 0.3f * sigma_new + 0.3f * (1.0f - 224.0f / 900.0f);

    const int i = blockIdx.x * 256 + threadIdx.x;
    const int l = labels[i];
    const float dsq = dist_sq[i];

    const float r_center = (l == 0) ? dsq : 0.0f;
    const float r_margin = (l == 1) ? fmaxf(m_adaptive - sqrtf(dsq), 0.0f) : 0.0f;

    const float sallv = S_all[i];
    const float s1v   = S_1[i];
    const float s0v   = sallv - s1v;
    const float pos = (l == 0) ? s0v : s1v;
    const float neg = (l == 0) ? s1v : s0v;

    const float n1 = (float)BB - n0;
    const float cnt_same = ((l == 0) ? n0 : n1) - 1.0f;
    const float cnt_diff = (l == 0) ? n1 : n0;

    float r_con = 0.0f;
    if (cnt_same > 0.0f && cnt_diff > 0.0f)
        r_con = logf(pos + neg + 1e-8f) - logf(pos);

    float tot = (r_center + r_margin + 0.5f * r_con) * (1.0f / (float)BB);

    #pragma unroll
    for (int m = 1; m < 64; m <<= 1) tot += __shfl_xor(tot, m);
    if ((threadIdx.x & 63) == 0) atomicAdd(out, tot);
}

// ---------------------------------------------------------------------------
// launch
// ---------------------------------------------------------------------------
extern "C" void kernel_launch(void* const* d_in, const int* in_sizes, int n_in,
                              void* d_out, int out_size, void* d_ws, size_t ws_size,
                              hipStream_t stream) {
    const float* feat   = (const float*)d_in[0];
    const int*   labels = (const int*)d_in[1];
    const float* center = (const float*)d_in[2];
    const float* rsigma = (const float*)d_in[3];
    float* out = (float*)d_out;

    char* ws = (char*)d_ws;
    __hip_bfloat16* fnf = (__hip_bfloat16*)ws;                    // B*D bf16 = 4 MB, fragment order
    float* dist_sq   = (float*)(ws + (size_t)BB * DD * 2);        // B floats
    float* S_all     = dist_sq + BB;                              // B floats
    float* S_1       = S_all + BB;                                // B floats
    float* stats_part= S_1 + BB;                                  // 2048*4 floats

    prep_kernel<<<dim3(BB / 4), dim3(256), 0, stream>>>(feat, labels, center, fnf,
                                                        dist_sq, stats_part, S_all, out);
    gram_kernel<<<dim3(1024), dim3(256), 0, stream>>>(fnf, labels, S_all, S_1);
    finalize_kernel<<<dim3(BB / 256), dim3(256), 0, stream>>>(labels, dist_sq, S_all, S_1,
                                                              stats_part, rsigma, out);
}

// Round 8
// 115.281 us; speedup vs baseline: 1.0206x; 1.0206x over previous
//
#include <hip/hip_runtime.h>
#include <hip/hip_bf16.h>

#define BB 8192
#define DD 256
#define ZN (2 * BB)   // floats to zero: S_all, S_1

typedef float f32x4 __attribute__((ext_vector_type(4)));
typedef __bf16 bf16x8 __attribute__((ext_vector_type(8)));

// sqrt(log2(e)/0.07): fn rows pre-scaled so MFMA acc = sim * log2(e)/T directly
#define FSCALE 4.53981600f

// raw v_exp_f32: args here are |x| <= ~21, no range fixup needed
__device__ __forceinline__ float fast_exp2(float x) {
    float r;
    asm("v_exp_f32 %0, %1" : "=v"(r) : "v"(x));
    return r;
}

// ---------------------------------------------------------------------------
// prep: one wave per row. dist_sq vs center, sigma partials (block-reduced,
// race-free into stats_part[block]), writes the normalized+scaled row in MFMA
// FRAGMENT ORDER. Also zeroes S_all/S_1/out.
// ---------------------------------------------------------------------------
__global__ __launch_bounds__(256) void prep_kernel(
    const float* __restrict__ feat, const int* __restrict__ labels,
    const float* __restrict__ center, __hip_bfloat16* __restrict__ fnf,
    float* __restrict__ dist_sq, float* __restrict__ stats_part,
    float* __restrict__ zacc, float* __restrict__ out)
{
    __shared__ float sh[3][4];
    const int gid = blockIdx.x * 256 + threadIdx.x;
    if (gid < ZN) zacc[gid] = 0.0f;
    if (gid == 0) out[0] = 0.0f;

    const int wave = threadIdx.x >> 6;
    const int lane = threadIdx.x & 63;
    const int row  = blockIdx.x * 4 + wave;

    const float4* frow = reinterpret_cast<const float4*>(feat + (size_t)row * DD);
    const float4* crow = reinterpret_cast<const float4*>(center);
    float4 x = frow[lane];
    float4 c = crow[lane];

    float d0 = x.x - c.x, d1 = x.y - c.y, d2 = x.z - c.z, d3 = x.w - c.w;
    float dsq = d0*d0 + d1*d1 + d2*d2 + d3*d3;
    float nsq = x.x*x.x + x.y*x.y + x.z*x.z + x.w*x.w;
    float sx  = x.x + x.y + x.z + x.w;

    #pragma unroll
    for (int m = 1; m < 64; m <<= 1) {
        dsq += __shfl_xor(dsq, m);
        nsq += __shfl_xor(nsq, m);
        sx  += __shfl_xor(sx,  m);
    }

    float rn = FSCALE / fmaxf(sqrtf(nsq), 1e-12f);

    ushort4 u;
    u.x = __builtin_bit_cast(unsigned short, __float2bfloat16(x.x * rn));
    u.y = __builtin_bit_cast(unsigned short, __float2bfloat16(x.y * rn));
    u.z = __builtin_bit_cast(unsigned short, __float2bfloat16(x.z * rn));
    u.w = __builtin_bit_cast(unsigned short, __float2bfloat16(x.w * rn));

    // lane holds elems e=4*lane..+3: kc=lane/8, quad=(lane%8)/2, half=lane&1
    const int g    = row >> 4;
    const int l15r = row & 15;
    const int kc   = lane >> 3;
    const int qd   = (lane & 7) >> 1;
    const int half = lane & 1;
    const size_t cell = (size_t)((g * 8 + kc) * 64 + qd * 16 + l15r);
    reinterpret_cast<ushort4*>(fnf)[cell * 2 + half] = u;

    if (lane == 0) {
        const float m0 = (labels[row] == 0) ? 1.0f : 0.0f;
        dist_sq[row] = dsq;
        sh[0][wave] = m0;
        sh[1][wave] = sx  * m0;
        sh[2][wave] = nsq * m0;
    }
    __syncthreads();
    if (threadIdx.x == 0) {
        float* sp = stats_part + (size_t)blockIdx.x * 4;
        sp[0] = sh[0][0] + sh[0][1] + sh[0][2] + sh[0][3];
        sp[1] = sh[1][0] + sh[1][1] + sh[1][2] + sh[1][3];
        sp[2] = sh[2][0] + sh[2][1] + sh[2][2] + sh[2][3];
        sp[3] = 0.0f;
    }
}

// ---------------------------------------------------------------------------
// gram v9: SYMMETRIC (upper-triangle) gram, v7/v8's barrier-free pipeline.
// Ablation ledger (v3..v8 all 44.5-53 us): structure class is at its ~765 TF
// ceiling; the remaining lever is WORK. e_ij == e_ji, so strictly-upper
// tiles credit each exp twice: row-side into S[i] (register sums, as before)
// and col-side into S[j] (per-lane 16-add + quad-fold shfl + atomic).
// S_1 col-side weights by the ROW label (wr[s][r]). Diag-range blocks
// (r in {2c,2c+1}) keep full row-side with j==i mask, no col-side; the two
// diag blocks per col-split cover both orientations of within-range pairs.
// Blocks: 128 rows x 256 cols, 4 waves x 32 rows, TILES=16.
// Grid: 64 diag + 992 upper = 1056 blocks (51.6% of full work).
// ---------------------------------------------------------------------------
#define LOAD4(BV, T, KB)                                                       \
  {                                                                            \
    _Pragma("unroll")                                                          \
    for (int k = 0; k < 4; ++k)                                                \
      BV[k] = F[((size_t)(cpanel + (T)) * 8 + (KB) + k) * 64 + lane];          \
  }

#define MFMA8(BV, KB)                                                          \
  {                                                                            \
    _Pragma("unroll")                                                          \
    for (int k = 0; k < 4; ++k) {                                              \
      acc[0] = __builtin_amdgcn_mfma_f32_16x16x32_bf16(a[0][(KB) + k], BV[k], acc[0], 0, 0, 0); \
      acc[1] = __builtin_amdgcn_mfma_f32_16x16x32_bf16(a[1][(KB) + k], BV[k], acc[1], 0, 0, 0); \
    }                                                                          \
  }

#define EPILOGUE(T)                                                            \
  {                                                                            \
    const int colbase = colstart + (T) * 16;                                   \
    const int bcol = colbase + l15;                                            \
    const float w1 = wlab[(T) * 16 + l15];                                     \
    if (isdiag && colbase + 16 > rowbase && colbase < rowbase + 32) {          \
      _Pragma("unroll")                                                        \
      for (int s = 0; s < 2; ++s)                                              \
        _Pragma("unroll")                                                      \
        for (int r = 0; r < 4; ++r) {                                          \
          const int rr = rowbase + s * 16 + quad * 4 + r;                      \
          float e = (rr == bcol) ? 0.0f : fast_exp2(acc[s][r]);                \
          sall[s][r] += e; sp1[s][r] = fmaf(e, w1, sp1[s][r]);                 \
        }                                                                      \
    } else {                                                                   \
      float ca = 0.0f, c1 = 0.0f;                                              \
      _Pragma("unroll")                                                        \
      for (int s = 0; s < 2; ++s)                                              \
        _Pragma("unroll")                                                      \
        for (int r = 0; r < 4; ++r) {                                          \
          float e = fast_exp2(acc[s][r]);                                      \
          sall[s][r] += e; sp1[s][r] = fmaf(e, w1, sp1[s][r]);                 \
          ca += e; c1 = fmaf(e, wr[s][r], c1);                                 \
        }                                                                      \
      if (!isdiag) {                                                           \
        ca += __shfl_xor(ca, 16); ca += __shfl_xor(ca, 32);                    \
        c1 += __shfl_xor(c1, 16); c1 += __shfl_xor(c1, 32);                    \
        if (quad == 0) {                                                       \
          atomicAdd(&S_all[bcol], ca);                                         \
          atomicAdd(&S_1[bcol],  c1);                                          \
        }                                                                      \
      }                                                                        \
    }                                                                          \
  }

__global__ __launch_bounds__(256, 4) void gram_kernel(
    const __hip_bfloat16* __restrict__ fnf, const int* __restrict__ labels,
    float* __restrict__ S_all, float* __restrict__ S_1)
{
    __shared__ float wlab[256];

    const int tid  = threadIdx.x;
    const int lane = tid & 63;
    const int wave = tid >> 6;
    const int l15  = lane & 15;
    const int quad = lane >> 4;

    // block -> (r, c): 64 diag blocks (r = bid, c = bid>>1), then upper list
    // for col-split c: 2c blocks at cumulative offset c*(c-1).
    const int bid = blockIdx.x;
    int r, c;
    bool isdiag;
    if (bid < 64) {
        r = bid; c = bid >> 1; isdiag = true;
    } else {
        const int e = bid - 64;
        int c0 = (int)((1.0f + sqrtf(1.0f + 4.0f * (float)e)) * 0.5f);
        while (c0 * (c0 - 1) > e) --c0;
        while ((c0 + 1) * c0 <= e) ++c0;
        c = c0; r = e - c0 * (c0 - 1); isdiag = false;
    }

    const int rowbase  = r * 128 + wave * 32;
    const int colstart = c * 256;
    const int cpanel   = colstart >> 4;  // first 16-col cell group

    const bf16x8* __restrict__ F = reinterpret_cast<const bf16x8*>(fnf);

    // A fragments: 2 sub-tiles x 8 k-chunks = 32 rows/wave, coalesced loads
    bf16x8 a[2][8];
    #pragma unroll
    for (int s = 0; s < 2; ++s)
        #pragma unroll
        for (int kc = 0; kc < 8; ++kc)
            a[s][kc] = F[(size_t)((((rowbase >> 4) + s) * 8 + kc)) * 64 + lane];

    // row labels for this lane's 8 accumulator rows (col-side S_1 weights)
    float wr[2][4];
    #pragma unroll
    for (int s = 0; s < 2; ++s)
        #pragma unroll
        for (int rr = 0; rr < 4; ++rr)
            wr[s][rr] = (float)labels[rowbase + s * 16 + quad * 4 + rr];

    float sall[2][4], sp1[2][4];
    #pragma unroll
    for (int s = 0; s < 2; ++s)
        #pragma unroll
        for (int rr = 0; rr < 4; ++rr) { sall[s][rr] = 0.0f; sp1[s][rr] = 0.0f; }

    if (tid < 256) wlab[tid] = (float)labels[colstart + tid];
    __syncthreads();        // the ONLY barrier; waves de-phase after this

    f32x4 acc[2];
    bf16x8 bvP[4], bvC[4];  // fixed roles: bvP = lo(next), bvC = hi(current)

    LOAD4(bvP, 0, 0);       // prefetch tile 0 lo-half

    #pragma unroll 1
    for (int t = 0; t < 15; ++t) {
        LOAD4(bvC, t, 4);           // current hi-half, in flight under MFMA-lo
        acc[0] = (f32x4){0,0,0,0}; acc[1] = (f32x4){0,0,0,0};
        MFMA8(bvP, 0);              // consume lo (prefetched last tile)
        LOAD4(bvP, t + 1, 0);       // prefetch next lo (WAR: after consume)
        MFMA8(bvC, 4);              // vmcnt wait for bvC folds under MFMA-lo
        EPILOGUE(t);
    }
    // t == 15
    LOAD4(bvC, 15, 4);
    acc[0] = (f32x4){0,0,0,0}; acc[1] = (f32x4){0,0,0,0};
    MFMA8(bvP, 0);
    MFMA8(bvC, 4);
    EPILOGUE(15);

    // row-side: reduce over the 16 cols held across low lane bits
    #pragma unroll
    for (int s = 0; s < 2; ++s)
        #pragma unroll
        for (int rr = 0; rr < 4; ++rr) {
            float va = sall[s][rr];
            float v1 = sp1[s][rr];
            #pragma unroll
            for (int m = 1; m < 16; m <<= 1) {
                va += __shfl_xor(va, m);
                v1 += __shfl_xor(v1, m);
            }
            if (l15 == 0) {
                const int grow = rowbase + s * 16 + quad * 4 + rr;
                atomicAdd(&S_all[grow], va);
                atomicAdd(&S_1[grow],  v1);
            }
        }
}

// ---------------------------------------------------------------------------
// finalize: fold 2048 sigma partials (redundantly per block, coalesced
// float4), then per-row losses + mean reduction into out[0].
// ---------------------------------------------------------------------------
__global__ __launch_bounds__(256) void finalize_kernel(
    const int* __restrict__ labels, const float* __restrict__ dist_sq,
    const float* __restrict__ S_all, const float* __restrict__ S_1,
    const float* __restrict__ stats_part, const float* __restrict__ rsigma,
    float* __restrict__ out)
{
    __shared__ float sh[3][4];
    const int lane = threadIdx.x & 63;
    const int wave = threadIdx.x >> 6;

    float c = 0.0f, s = 0.0f, q = 0.0f;
    const float4* sp = reinterpret_cast<const float4*>(stats_part);
    #pragma unroll
    for (int b = 0; b < 8; ++b) {
        const float4 v = sp[b * 256 + threadIdx.x];
        c += v.x; s += v.y; q += v.z;
    }
    #pragma unroll
    for (int m = 1; m < 64; m <<= 1) {
        c += __shfl_xor(c, m);
        s += __shfl_xor(s, m);
        q += __shfl_xor(q, m);
    }
    if (lane == 0) { sh[0][wave] = c; sh[1][wave] = s; sh[2][wave] = q; }
    __syncthreads();

    const float n0   = sh[0][0] + sh[0][1] + sh[0][2] + sh[0][3];
    const float ssx  = sh[1][0] + sh[1][1] + sh[1][2] + sh[1][3];
    const float snsq = sh[2][0] + sh[2][1] + sh[2][2] + sh[2][3];

    const float n_el = n0 * (float)DD;
    const float mean = ssx / n_el;
    const float var  = (snsq - n_el * mean * mean) / (n_el - 1.0f);
    const float sigma_new  = 0.9f * rsigma[0] + 0.1f * sqrtf(var);
    const float m_adaptive = 0.5f + 0.3f * sigma_new + 0.3f * (1.0f - 224.0f / 900.0f);

    const int i = blockIdx.x * 256 + threadIdx.x;
    const int l = labels[i];
    const float dsq = dist_sq[i];

    const float r_center = (l == 0) ? dsq : 0.0f;
    const float r_margin = (l == 1) ? fmaxf(m_adaptive - sqrtf(dsq), 0.0f) : 0.0f;

    const float sallv = S_all[i];
    const float s1v   = S_1[i];
    const float s0v   = sallv - s1v;
    const float pos = (l == 0) ? s0v : s1v;
    const float neg = (l == 0) ? s1v : s0v;

    const float n1 = (float)BB - n0;
    const float cnt_same = ((l == 0) ? n0 : n1) - 1.0f;
    const float cnt_diff = (l == 0) ? n1 : n0;

    float r_con = 0.0f;
    if (cnt_same > 0.0f && cnt_diff > 0.0f)
        r_con = logf(pos + neg + 1e-8f) - logf(pos);

    float tot = (r_center + r_margin + 0.5f * r_con) * (1.0f / (float)BB);

    #pragma unroll
    for (int m = 1; m < 64; m <<= 1) tot += __shfl_xor(tot, m);
    if ((threadIdx.x & 63) == 0) atomicAdd(out, tot);
}

// ---------------------------------------------------------------------------
// launch
// ---------------------------------------------------------------------------
extern "C" void kernel_launch(void* const* d_in, const int* in_sizes, int n_in,
                              void* d_out, int out_size, void* d_ws, size_t ws_size,
                              hipStream_t stream) {
    const float* feat   = (const float*)d_in[0];
    const int*   labels = (const int*)d_in[1];
    const float* center = (const float*)d_in[2];
    const float* rsigma = (const float*)d_in[3];
    float* out = (float*)d_out;

    char* ws = (char*)d_ws;
    __hip_bfloat16* fnf = (__hip_bfloat16*)ws;                    // B*D bf16 = 4 MB, fragment order
    float* dist_sq   = (float*)(ws + (size_t)BB * DD * 2);        // B floats
    float* S_all     = dist_sq + BB;                              // B floats
    float* S_1       = S_all + BB;                                // B floats
    float* stats_part= S_1 + BB;                                  // 2048*4 floats

    prep_kernel<<<dim3(BB / 4), dim3(256), 0, stream>>>(feat, labels, center, fnf,
                                                        dist_sq, stats_part, S_all, out);
    gram_kernel<<<dim3(1056), dim3(256), 0, stream>>>(fnf, labels, S_all, S_1);
    finalize_kernel<<<dim3(BB / 256), dim3(256), 0, stream>>>(labels, dist_sq, S_all, S_1,
                                                              stats_part, rsigma, out);
}